// Round 2
// baseline (100.850 us; speedup 1.0000x reference)
//
#include <hip/hip_runtime.h>
#include <math.h>

// Problem constants
#define BB 2
#define LL 1024
#define SS 1024
#define HH 8
#define DD 64
#define PP 4

// Tiling for attn kernel
#define TL 16        // l-rows per block
#define TS 64        // s per tile
#define NT (SS/TS)   // 16 tiles
#define VSTRIDE 68   // padded vbuf row stride (floats)

// cos(2*pi*x) via hardware v_cos (input in revolutions)
#if __has_builtin(__builtin_amdgcn_cosf)
#define COS2PI(x) __builtin_amdgcn_cosf(x)
#else
#define COS2PI(x) __cosf((x) * 6.283185307179586f)
#endif
#if __has_builtin(__builtin_amdgcn_exp2f)
#define EXP2F(x) __builtin_amdgcn_exp2f(x)
#else
#define EXP2F(x) exp2f(x)
#endif

// params are pre-scaled by 1/(4*pi): q' = tanh(...)/4, so
// cos(2*pi*(q'-k')) = cos(0.5*(q_param - k_param))  (exact)
// e = exp(prod/8) = exp2(prod * log2(e)/8)
__device__ __forceinline__ float score_e(float4 q, float4 k) {
    float c0 = COS2PI(q.x - k.x);
    float c1 = COS2PI(q.y - k.y);
    float c2 = COS2PI(q.z - k.z);
    float c3 = COS2PI(q.w - k.w);
    float prod = (c0 * c1) * (c2 * c3);
    return EXP2F(prod * 0.18033688011112042f); // log2(e)/8
}

// ---------------- Kernel A: angle params ----------------
// One wave per row. Rows [0, B*L*H) -> q rows; [B*L*H, 2*B*L*H) -> k rows.
// Output layout transposed: [B][H][L][P], values tanh(x.W+b)*0.25
__global__ __launch_bounds__(256) void qka_params_kernel(
    const float* __restrict__ Q, const float* __restrict__ K,
    const float* __restrict__ Wq, const float* __restrict__ bq,
    const float* __restrict__ Wk, const float* __restrict__ bk,
    float* __restrict__ qp_ws, float* __restrict__ kp_ws)
{
    const int wid  = (blockIdx.x * blockDim.x + threadIdx.x) >> 6;
    const int lane = threadIdx.x & 63;
    const int NQ = BB * LL * HH;      // 16384
    const bool is_q = (wid < NQ);
    const int r = is_q ? wid : wid - NQ;

    // r = (b*L + l)*H + h
    const int b   = r >> 13;          // / (1024*8)
    const int rem = r & 8191;
    const int l   = rem >> 3;
    const int h   = rem & 7;

    const float* in   = is_q ? Q  : K;
    const float* W    = is_q ? Wq : Wk;
    const float* bias = is_q ? bq : bk;

    float x = in[(size_t)r * DD + lane];
    float4 w = *reinterpret_cast<const float4*>(W + lane * PP); // W[d][p], d=lane
    float p0 = x * w.x, p1 = x * w.y, p2 = x * w.z, p3 = x * w.w;
    #pragma unroll
    for (int off = 1; off < 64; off <<= 1) {
        p0 += __shfl_xor(p0, off);
        p1 += __shfl_xor(p1, off);
        p2 += __shfl_xor(p2, off);
        p3 += __shfl_xor(p3, off);
    }
    if (lane < PP) {
        float s = (lane == 0) ? p0 : (lane == 1) ? p1 : (lane == 2) ? p2 : p3;
        float v = 0.25f * tanhf(s + bias[lane]);
        float* outp = is_q ? qp_ws : kp_ws;
        outp[(((size_t)(b * HH + h)) * LL + l) * PP + lane] = v;
    }
}

// ---------------- Kernel B: scores + softmax + attn write + PV ----------------
// grid = B*H*(L/TL) = 1024 blocks, 256 threads, 38208 B dynamic LDS -> 4 blocks/CU
__global__ __launch_bounds__(256) void qka_attn_kernel(
    const float* __restrict__ V,       // [B,S,H,D]
    const float* __restrict__ qp_ws,   // [B,H,L,P]
    const float* __restrict__ kp_ws,   // [B,H,S,P]
    float* __restrict__ out_ctx,       // [B,L,H,D]
    float* __restrict__ out_attn)      // [B,H,L,S]
{
    extern __shared__ __align__(16) float smem[];
    float* kp   = smem;                 // [S][P]             4096 floats
    float* qp   = kp + SS * PP;         // [TL][P]            64
    float* rcpZ = qp + TL * PP;         // [16]               16
    float* wbuf = rcpZ + 16;            // [TL][TS]           1024
    float* vbuf = wbuf + TL * TS;       // [TS][VSTRIDE]      4352
    // total 9552 floats = 38208 B; ctx-reduce (8192 floats) aliases smem

    const int t   = threadIdx.x;
    const int bid = blockIdx.x;
    const int lt  = bid & (LL / TL - 1);   // 0..63
    const int h   = (bid >> 6) & 7;
    const int b   = bid >> 9;

    // ---- stage k-params (full S) and q-params (TL rows) ----
    const float* kp_src = kp_ws + ((size_t)(b * HH + h)) * SS * PP;
    #pragma unroll
    for (int i = 0; i < 4; ++i) {
        int n = i * 256 + t; // float4 index, 1024 total
        *reinterpret_cast<float4*>(kp + n * 4) =
            reinterpret_cast<const float4*>(kp_src)[n];
    }
    const float* qp_src = qp_ws + (((size_t)(b * HH + h)) * LL + lt * TL) * PP;
    if (t < TL * PP) qp[t] = qp_src[t];
    __syncthreads();

    // ---- pass 1: row sums Z (recompute later is cheaper than renormalizing 67MB) ----
    {
        const int row = t >> 4;        // 0..15
        const int l16 = t & 15;
        float4 q4 = *reinterpret_cast<const float4*>(qp + row * PP);
        float zsum = 0.f;
        #pragma unroll 8
        for (int j = 0; j < SS / 16; ++j) {
            int s = l16 + j * 16;
            float4 k4 = *reinterpret_cast<const float4*>(kp + s * PP);
            zsum += score_e(q4, k4);
        }
        zsum += __shfl_xor(zsum, 1);
        zsum += __shfl_xor(zsum, 2);
        zsum += __shfl_xor(zsum, 4);
        zsum += __shfl_xor(zsum, 8);
        if (l16 == 0) rcpZ[row] = 1.0f / zsum;
    }

    // ---- pass 2: per s-tile: phase A (w -> LDS + attn store), phase B (PV) ----
    const int rg = t >> 6;          // wave id: rows rg*4 .. rg*4+3
    const int dg = (t >> 3) & 7;    // d block: d = dg*8 .. dg*8+7
    const int sc = t & 7;           // s sub-chunk: s = it*8 + sc

    float acc[4][8];
    #pragma unroll
    for (int i = 0; i < 4; ++i)
        #pragma unroll
        for (int j = 0; j < 8; ++j) acc[i][j] = 0.f;

    for (int tile = 0; tile < NT; ++tile) {
        const int s0 = tile * TS;

        // issue V tile loads early (4 float4 per thread; 64 s x 64 d)
        float4 vreg[4];
        #pragma unroll
        for (int i = 0; i < 4; ++i) {
            int n  = i * 256 + t;   // float4 linear idx in tile (1024 total)
            int s  = n >> 4;        // 0..63
            int dq = n & 15;
            vreg[i] = *reinterpret_cast<const float4*>(
                V + (((size_t)(b * SS + s0 + s)) * HH + h) * DD + dq * 4);
        }

        __syncthreads(); // previous phase B finished reading wbuf/vbuf

        // phase A: thread handles s_local = t&63, rows lh*4..lh*4+3
        {
            const int sl = t & 63;
            const int lh = t >> 6;
            float4 k4 = *reinterpret_cast<const float4*>(kp + (s0 + sl) * PP);
            float* attn_base = out_attn +
                (((size_t)(b * HH + h)) * LL + lt * TL + lh * 4) * SS + s0 + sl;
            #pragma unroll
            for (int i = 0; i < 4; ++i) {
                int l = lh * 4 + i;
                float4 q4 = *reinterpret_cast<const float4*>(qp + l * PP);
                float e = score_e(q4, k4);
                float w = e * rcpZ[l];
                wbuf[l * TS + sl] = w;
                __builtin_nontemporal_store(w, attn_base + (size_t)i * SS);
            }
        }

        // commit V tile to LDS (padded stride 68)
        #pragma unroll
        for (int i = 0; i < 4; ++i) {
            int n  = i * 256 + t;
            int s  = n >> 4;
            int dq = n & 15;
            *reinterpret_cast<float4*>(vbuf + s * VSTRIDE + dq * 4) = vreg[i];
        }
        __syncthreads();

        // phase B: register-tiled PV, 32 FMA per 6 LDS reads
        #pragma unroll
        for (int it = 0; it < TS / 8; ++it) {
            int s = it * 8 + sc;
            float w4[4];
            #pragma unroll
            for (int i = 0; i < 4; ++i) w4[i] = wbuf[(rg * 4 + i) * TS + s];
            float4 va = *reinterpret_cast<const float4*>(vbuf + s * VSTRIDE + dg * 8);
            float4 vb = *reinterpret_cast<const float4*>(vbuf + s * VSTRIDE + dg * 8 + 4);
            #pragma unroll
            for (int i = 0; i < 4; ++i) {
                acc[i][0] += w4[i] * va.x;
                acc[i][1] += w4[i] * va.y;
                acc[i][2] += w4[i] * va.z;
                acc[i][3] += w4[i] * va.w;
                acc[i][4] += w4[i] * vb.x;
                acc[i][5] += w4[i] * vb.y;
                acc[i][6] += w4[i] * vb.z;
                acc[i][7] += w4[i] * vb.w;
            }
        }
    }

    // ---- reduce the 8 s-chunk partial contexts and store ----
    __syncthreads();
    float* ctxbuf = smem; // [8(sc)][TL][DD] = 8192 floats, aliases everything
    #pragma unroll
    for (int i = 0; i < 4; ++i) {
        float* p = ctxbuf + ((sc * TL) + rg * 4 + i) * DD + dg * 8;
        *reinterpret_cast<float4*>(p)     = make_float4(acc[i][0], acc[i][1], acc[i][2], acc[i][3]);
        *reinterpret_cast<float4*>(p + 4) = make_float4(acc[i][4], acc[i][5], acc[i][6], acc[i][7]);
    }
    __syncthreads();
    #pragma unroll
    for (int k = 0; k < 4; ++k) {
        int o = k * 256 + t;  // 0..1023
        int l = o >> 6;
        int d = o & 63;
        float ssum = 0.f;
        #pragma unroll
        for (int scc = 0; scc < 8; ++scc) ssum += ctxbuf[scc * (TL * DD) + o];
        __builtin_nontemporal_store(ssum,
            out_ctx + (((size_t)(b * LL + lt * TL + l)) * HH + h) * DD + d);
    }
}

extern "C" void kernel_launch(void* const* d_in, const int* in_sizes, int n_in,
                              void* d_out, int out_size, void* d_ws, size_t ws_size,
                              hipStream_t stream) {
    const float* Q  = (const float*)d_in[0];
    const float* K  = (const float*)d_in[1];
    const float* V  = (const float*)d_in[2];
    const float* Wq = (const float*)d_in[3];
    const float* bq = (const float*)d_in[4];
    const float* Wk = (const float*)d_in[5];
    const float* bk = (const float*)d_in[6];

    float* out_ctx  = (float*)d_out;                           // [B,L,H,D]
    float* out_attn = out_ctx + (size_t)BB * LL * HH * DD;     // [B,H,L,S]

    float* qp_ws = (float*)d_ws;                               // 65536 floats
    float* kp_ws = qp_ws + (size_t)BB * HH * LL * PP;          // 65536 floats

    // Kernel A: 32768 rows, one wave each, 4 waves/block
    qka_params_kernel<<<8192, 256, 0, stream>>>(Q, K, Wq, bq, Wk, bk, qp_ws, kp_ws);

    // Kernel B: 1024 blocks, 38208 B dynamic LDS -> 4 blocks/CU
    const int smem_bytes = (SS * PP + TL * PP + 16 + TL * TS + TS * VSTRIDE) * 4;
    qka_attn_kernel<<<BB * HH * (LL / TL), 256, smem_bytes, stream>>>(
        V, qp_ws, kp_ws, out_ctx, out_attn);
}

// Round 4
// 43.197 us; speedup vs baseline: 2.3347x; 2.3347x over previous
//
#include <hip/hip_runtime.h>
#include <math.h>

#define BB 2
#define LL 1024
#define SS 1024
#define HH 8
#define DD 64
#define PP 4
#define TL 16

typedef __attribute__((ext_vector_type(8))) short short8;
typedef __attribute__((ext_vector_type(4))) float floatx4;

#if __has_builtin(__builtin_amdgcn_cosf)
#define COS2PI(x) __builtin_amdgcn_cosf(x)
#else
#define COS2PI(x) __cosf((x) * 6.283185307179586f)
#endif
#if __has_builtin(__builtin_amdgcn_exp2f)
#define EXP2F(x) __builtin_amdgcn_exp2f(x)
#else
#define EXP2F(x) exp2f(x)
#endif

// params pre-scaled by 1/(4*pi): q' = tanh(.)/4 so cos(2*pi*(q'-k')) = cos((qp-kp)/2)
__device__ __forceinline__ float scoreP(float4 q, float k0, float k1, float k2, float k3) {
    float c0 = COS2PI(q.x - k0);
    float c1 = COS2PI(q.y - k1);
    float c2 = COS2PI(q.z - k2);
    float c3 = COS2PI(q.w - k3);
    float prod = (c0 * c1) * (c2 * c3);
    return EXP2F(prod * 0.18033688011112042f); // exp(prod/8) ; log2(e)/8
}

__device__ __forceinline__ unsigned f2bf(float f) {   // RNE float->bf16 (low 16 of result)
    unsigned u = __float_as_uint(f);
    u += 0x7FFF + ((u >> 16) & 1);
    return u >> 16;
}
__device__ __forceinline__ float bf2f(unsigned u) { return __uint_as_float(u << 16); }

// ---------------- Kernel 1: angle params (blocks 0..8191) + V transpose->bf16 (blocks 8192..8447) ----------------
__global__ __launch_bounds__(256) void qka_prep_kernel(
    const float* __restrict__ Q, const float* __restrict__ K, const float* __restrict__ V,
    const float* __restrict__ Wq, const float* __restrict__ bq,
    const float* __restrict__ Wk, const float* __restrict__ bk,
    float* __restrict__ qp_ws, float* __restrict__ kp_ws, unsigned short* __restrict__ vt_ws)
{
    __shared__ float vt[64 * 66];   // used only by transpose blocks
    const int bid = blockIdx.x;
    const int t = threadIdx.x;

    if (bid < 8192) {
        // ---- params: one wave per row; rows [0,16384) q, [16384,32768) k ----
        const int wid  = (bid * 256 + t) >> 6;
        const int lane = t & 63;
        const int NQ = BB * LL * HH;          // 16384
        const bool is_q = (wid < NQ);
        const int r = is_q ? wid : wid - NQ;
        const int b   = r >> 13;
        const int rem = r & 8191;
        const int l   = rem >> 3;
        const int h   = rem & 7;

        const float* in   = is_q ? Q  : K;
        const float* W    = is_q ? Wq : Wk;
        const float* bias = is_q ? bq : bk;

        float x = in[(size_t)r * DD + lane];
        float4 w = *reinterpret_cast<const float4*>(W + lane * PP);
        float p0 = x * w.x, p1 = x * w.y, p2 = x * w.z, p3 = x * w.w;
        #pragma unroll
        for (int off = 1; off < 64; off <<= 1) {
            p0 += __shfl_xor(p0, off);
            p1 += __shfl_xor(p1, off);
            p2 += __shfl_xor(p2, off);
            p3 += __shfl_xor(p3, off);
        }
        if (lane < PP) {
            float s = (lane == 0) ? p0 : (lane == 1) ? p1 : (lane == 2) ? p2 : p3;
            float v = 0.25f * tanhf(s + bias[lane]);
            float* outp = is_q ? qp_ws : kp_ws;
            outp[(((size_t)(b * HH + h)) * LL + l) * PP + lane] = v;
        }
    } else {
        // ---- V transpose tile: (b,h, s-tile of 64) -> vt_ws[b][h][d][s] bf16 ----
        const int tile = bid - 8192;          // 0..255
        const int b  = tile >> 7;
        const int h  = (tile >> 4) & 7;
        const int s0 = (tile & 15) * 64;
        const int bh = b * HH + h;

        // stage transposed into LDS: vt[d][s] (stride 66)
        #pragma unroll
        for (int i = 0; i < 4; ++i) {
            int n = i * 256 + t;              // 0..1023 float4s
            int s = n >> 4, dq = n & 15;
            float4 v = *reinterpret_cast<const float4*>(
                V + (((size_t)(b * SS + s0 + s)) * HH + h) * DD + dq * 4);
            vt[(dq * 4 + 0) * 66 + s] = v.x;
            vt[(dq * 4 + 1) * 66 + s] = v.y;
            vt[(dq * 4 + 2) * 66 + s] = v.z;
            vt[(dq * 4 + 3) * 66 + s] = v.w;
        }
        __syncthreads();
        // pack bf16 pairs, coalesced store: u32 idx = (bh*64+d)*512 + s0/2 + sp
        unsigned* outp = reinterpret_cast<unsigned*>(vt_ws);
        #pragma unroll
        for (int rr = 0; rr < 8; ++rr) {
            int idx = rr * 256 + t;           // 0..2047
            int d = idx >> 5, sp = idx & 31;
            float a = vt[d * 66 + 2 * sp];
            float c = vt[d * 66 + 2 * sp + 1];
            unsigned pk = f2bf(a) | (f2bf(c) << 16);
            outp[((size_t)bh * DD + d) * (SS / 2) + (s0 >> 1) + sp] = pk;
        }
    }
}

// ---------------- Kernel 2: scores + softmax + attn write + MFMA PV ----------------
// grid 1024 = (b,h,lt), 256 thr, static LDS 40960B -> 4 blocks/CU
__global__ __launch_bounds__(256) void qka_main_kernel(
    const float* __restrict__ qp_ws,          // [B,H,L,P] fp32
    const float* __restrict__ kp_ws,          // [B,H,S,P] fp32
    const unsigned short* __restrict__ vt_ws, // [B,H,D,S] bf16
    float* __restrict__ out_ctx,              // [B,L,H,D]
    float* __restrict__ out_attn)             // [B,H,L,S]
{
    __shared__ unsigned short kp[SS * PP];    // 8192 B, bf16 params
    __shared__ unsigned short Pm[TL * SS];    // 32768 B, bf16 P then w (XOR-swizzled)

    const int t   = threadIdx.x;
    const int bid = blockIdx.x;
    const int lt  = bid & 63;
    const int h   = (bid >> 6) & 7;
    const int b   = bid >> 9;
    const int bh  = b * HH + h;

    // ---- stage kp as bf16 ----
    const float4* kps = reinterpret_cast<const float4*>(kp_ws + (size_t)bh * SS * PP);
    #pragma unroll
    for (int r = 0; r < 4; ++r) {
        int s = r * 256 + t;
        float4 kv = kps[s];
        uint2 pk;
        pk.x = f2bf(kv.x) | (f2bf(kv.y) << 16);
        pk.y = f2bf(kv.z) | (f2bf(kv.w) << 16);
        *reinterpret_cast<uint2*>(&kp[s * 4]) = pk;
    }
    __syncthreads();

    const int wv = t >> 6, lane = t & 63;
    const int r0 = wv * 4;                    // this wave owns rows r0..r0+3

    // ---- q params for the wave's 4 rows ----
    float4 q4[4];
    #pragma unroll
    for (int i = 0; i < 4; ++i)
        q4[i] = *reinterpret_cast<const float4*>(
            qp_ws + ((size_t)bh * LL + lt * TL + r0 + i) * PP);

    // ---- pass A: P = exp(score) -> LDS bf16, Z accumulated in regs ----
    float zacc[4] = {0.f, 0.f, 0.f, 0.f};
    for (int c = 0; c < 8; ++c) {
        int s = c * 128 + lane * 2;
        uint4 kk = *reinterpret_cast<const uint4*>(&kp[s * 4]);  // params of s, s+1
        float ka0 = bf2f(kk.x & 0xffffu), ka1 = bf2f(kk.x >> 16);
        float ka2 = bf2f(kk.y & 0xffffu), ka3 = bf2f(kk.y >> 16);
        float kb0 = bf2f(kk.z & 0xffffu), kb1 = bf2f(kk.z >> 16);
        float kb2 = bf2f(kk.w & 0xffffu), kb3 = bf2f(kk.w >> 16);
        #pragma unroll
        for (int i = 0; i < 4; ++i) {
            float e0 = scoreP(q4[i], ka0, ka1, ka2, ka3);
            float e1 = scoreP(q4[i], kb0, kb1, kb2, kb3);
            zacc[i] += e0 + e1;
            unsigned pk = f2bf(e0) | (f2bf(e1) << 16);
            int row = r0 + i;
            unsigned byte = (unsigned)(row * 2048 + c * 256 + lane * 4) ^ ((row & 7) << 4);
            *reinterpret_cast<unsigned*>(reinterpret_cast<char*>(Pm) + byte) = pk;
        }
    }

    // ---- Z reduce (wave-private rows, no barrier) ----
    #pragma unroll
    for (int i = 0; i < 4; ++i) {
        float z = zacc[i];
        #pragma unroll
        for (int off = 1; off < 64; off <<= 1) z += __shfl_xor(z, off);
        zacc[i] = 1.0f / z;
    }

    // ---- store pass: attn fp32 out + write back normalized bf16 w into Pm ----
    #pragma unroll
    for (int i = 0; i < 4; ++i) {
        int row = r0 + i;
        float rz = zacc[i];
        unsigned sw = (row & 7) << 4;
        float* abase = out_attn + ((size_t)bh * LL + lt * TL + row) * SS;
        #pragma unroll
        for (int it = 0; it < 4; ++it) {
            unsigned byte = (unsigned)(row * 2048 + it * 512 + lane * 8) ^ sw;
            uint2 pk = *reinterpret_cast<uint2*>(reinterpret_cast<char*>(Pm) + byte);
            float w0 = bf2f(pk.x & 0xffffu) * rz, w1 = bf2f(pk.x >> 16) * rz;
            float w2 = bf2f(pk.y & 0xffffu) * rz, w3 = bf2f(pk.y >> 16) * rz;
            floatx4 wv4 = {w0, w1, w2, w3};
            __builtin_nontemporal_store(wv4,
                reinterpret_cast<floatx4*>(abase + it * 256 + lane * 4));
            uint2 wb;
            wb.x = f2bf(w0) | (f2bf(w1) << 16);
            wb.y = f2bf(w2) | (f2bf(w3) << 16);
            *reinterpret_cast<uint2*>(reinterpret_cast<char*>(Pm) + byte) = wb;
        }
    }
    __syncthreads();   // all rows' w visible to all waves

    // ---- PV: ctx[16 l][64 d] via mfma 16x16x32 bf16; wave wv -> d0 = wv*16 ----
    const int d0 = wv * 16;
    const int fr = lane & 15;     // A row (l), B col (d)
    const int hi = lane >> 4;     // k-group
    floatx4 acc = {0.f, 0.f, 0.f, 0.f};
    const unsigned short* vtb = vt_ws + ((size_t)bh * DD + d0 + fr) * SS + hi * 8;
    const unsigned swf = (unsigned)((fr & 7) << 4);
    #pragma unroll 4
    for (int st = 0; st < 32; ++st) {
        unsigned abyte = (unsigned)(fr * 2048 + st * 64 + hi * 16) ^ swf;
        short8 afrag = *reinterpret_cast<const short8*>(
            reinterpret_cast<char*>(Pm) + abyte);
        short8 bfrag = *reinterpret_cast<const short8*>(vtb + st * 32);
        acc = __builtin_amdgcn_mfma_f32_16x16x32_bf16(afrag, bfrag, acc, 0, 0, 0);
    }
    // D: row m = hi*4 + r, col n = fr
    #pragma unroll
    for (int r = 0; r < 4; ++r) {
        int l = lt * TL + hi * 4 + r;
        __builtin_nontemporal_store(acc[r],
            out_ctx + (((size_t)b * LL + l) * HH + h) * DD + d0 + fr);
    }
}

extern "C" void kernel_launch(void* const* d_in, const int* in_sizes, int n_in,
                              void* d_out, int out_size, void* d_ws, size_t ws_size,
                              hipStream_t stream) {
    const float* Q  = (const float*)d_in[0];
    const float* K  = (const float*)d_in[1];
    const float* V  = (const float*)d_in[2];
    const float* Wq = (const float*)d_in[3];
    const float* bq = (const float*)d_in[4];
    const float* Wk = (const float*)d_in[5];
    const float* bk = (const float*)d_in[6];

    float* out_ctx  = (float*)d_out;                           // [B,L,H,D]
    float* out_attn = out_ctx + (size_t)BB * LL * HH * DD;     // [B,H,L,S]

    float* qp_ws = (float*)d_ws;                               // 256 KB
    float* kp_ws = qp_ws + (size_t)BB * HH * LL * PP;          // 256 KB
    unsigned short* vt_ws = (unsigned short*)(kp_ws + (size_t)BB * HH * SS * PP); // 2 MB bf16 V^T

    // K1: params (8192 blocks) + V transpose (256 blocks)
    qka_prep_kernel<<<8448, 256, 0, stream>>>(Q, K, V, Wq, bq, Wk, bk, qp_ws, kp_ws, vt_ws);

    // K2: fused scores/softmax/attn/PV
    qka_main_kernel<<<BB * HH * (LL / TL), 256, 0, stream>>>(
        qp_ws, kp_ws, vt_ws, out_ctx, out_attn);
}

// Round 5
// 35.452 us; speedup vs baseline: 2.8447x; 1.2184x over previous
//
#include <hip/hip_runtime.h>
#include <math.h>

#define BB 2
#define LL 1024
#define SS 1024
#define HH 8
#define DD 64
#define PP 4
#define TL 16

typedef __attribute__((ext_vector_type(8))) short short8;
typedef __attribute__((ext_vector_type(4))) float floatx4;
typedef __attribute__((ext_vector_type(2))) float floatx2;

#if __has_builtin(__builtin_amdgcn_cosf)
#define COS2PI(x) __builtin_amdgcn_cosf(x)
#else
#define COS2PI(x) __cosf((x) * 6.283185307179586f)
#endif
#if __has_builtin(__builtin_amdgcn_exp2f)
#define EXP2F(x) __builtin_amdgcn_exp2f(x)
#else
#define EXP2F(x) exp2f(x)
#endif

// params pre-scaled by 1/(4*pi): q' = tanh(.)/4 so cos(2*pi*(q'-k')) = cos((qp-kp)/2)
__device__ __forceinline__ float scoreP(float4 q, float k0, float k1, float k2, float k3) {
    float c0 = COS2PI(q.x - k0);
    float c1 = COS2PI(q.y - k1);
    float c2 = COS2PI(q.z - k2);
    float c3 = COS2PI(q.w - k3);
    float prod = (c0 * c1) * (c2 * c3);
    return EXP2F(prod * 0.18033688011112042f); // exp(prod/8) ; log2(e)/8
}

// RNE pack of two f32 -> u32 (lo = a, hi = b), single HW instr
__device__ __forceinline__ unsigned cvt_pk_bf16(float a, float b) {
    unsigned r;
    asm("v_cvt_pk_bf16_f32 %0, %1, %2" : "=v"(r) : "v"(a), "v"(b));
    return r;
}
__device__ __forceinline__ float bf2f(unsigned u) { return __uint_as_float(u << 16); }

// ---------------- Kernel 1: prep ----------------
// blocks 0..255:   q-param tiles (64 rows each)
// blocks 256..511: k-param tiles
// blocks 512..767: V transpose -> bf16 [B,H,D,S]
__global__ __launch_bounds__(256) void qka_prep_kernel(
    const float* __restrict__ Q, const float* __restrict__ K, const float* __restrict__ V,
    const float* __restrict__ Wq, const float* __restrict__ bq,
    const float* __restrict__ Wk, const float* __restrict__ bk,
    float* __restrict__ qp_ws, float* __restrict__ kp_ws, unsigned short* __restrict__ vt_ws)
{
    __shared__ float sm[4480];          // params: [64*65] tile + [256] W ; transpose: [64*66]
    const int bid = blockIdx.x;
    const int t = threadIdx.x;

    if (bid < 512) {
        // ---- params: 64 rows per block; thread = (row = t&63, p = t>>6) ----
        const bool is_q = (bid < 256);
        const int r_base = (is_q ? bid : bid - 256) * 64;
        const float* in   = is_q ? Q  : K;
        const float* W    = is_q ? Wq : Wk;
        const float* bias = is_q ? bq : bk;

        float* tile = sm;               // [64][65]
        float* Wl   = sm + 64 * 65;     // [256]

        // stage 64x64 input tile (coalesced float4 reads, scalar LDS writes)
        #pragma unroll
        for (int i = 0; i < 4; ++i) {
            int n = i * 256 + t;        // float4 index
            int row = n >> 4, dq = n & 15;
            float4 v = *reinterpret_cast<const float4*>(in + ((size_t)(r_base + row)) * DD + dq * 4);
            tile[row * 65 + dq * 4 + 0] = v.x;
            tile[row * 65 + dq * 4 + 1] = v.y;
            tile[row * 65 + dq * 4 + 2] = v.z;
            tile[row * 65 + dq * 4 + 3] = v.w;
        }
        Wl[t] = W[t];                   // 256 = DD*PP exactly
        __syncthreads();

        const int row = t & 63;
        const int p   = t >> 6;         // wave-uniform
        float acc = 0.f;
        #pragma unroll 16
        for (int d = 0; d < DD; ++d)
            acc += tile[row * 65 + d] * Wl[d * PP + p];

        const int r = r_base + row;     // r = (b*L + l)*H + h
        const int b   = r >> 13;
        const int l   = (r & 8191) >> 3;
        const int h   = r & 7;
        float v = 0.25f * tanhf(acc + bias[p]);
        float* outp = is_q ? qp_ws : kp_ws;
        outp[(((size_t)(b * HH + h)) * LL + l) * PP + p] = v;
    } else {
        // ---- V transpose tile: (b,h, s-tile of 64) -> vt_ws[b][h][d][s] bf16 ----
        const int tile_i = bid - 512;       // 0..255
        const int b  = tile_i >> 7;
        const int h  = (tile_i >> 4) & 7;
        const int s0 = (tile_i & 15) * 64;
        const int bh = b * HH + h;
        float* vt = sm;                      // [64][66]

        #pragma unroll
        for (int i = 0; i < 4; ++i) {
            int n = i * 256 + t;
            int s = n >> 4, dq = n & 15;
            float4 v = *reinterpret_cast<const float4*>(
                V + (((size_t)(b * SS + s0 + s)) * HH + h) * DD + dq * 4);
            vt[(dq * 4 + 0) * 66 + s] = v.x;
            vt[(dq * 4 + 1) * 66 + s] = v.y;
            vt[(dq * 4 + 2) * 66 + s] = v.z;
            vt[(dq * 4 + 3) * 66 + s] = v.w;
        }
        __syncthreads();
        unsigned* outp = reinterpret_cast<unsigned*>(vt_ws);
        #pragma unroll
        for (int rr = 0; rr < 8; ++rr) {
            int idx = rr * 256 + t;          // 0..2047
            int d = idx >> 5, sp = idx & 31;
            unsigned pk = cvt_pk_bf16(vt[d * 66 + 2 * sp], vt[d * 66 + 2 * sp + 1]);
            outp[((size_t)bh * DD + d) * (SS / 2) + (s0 >> 1) + sp] = pk;
        }
    }
}

// ---------------- Kernel 2: scores + softmax + attn write + MFMA PV ----------------
// grid 1024 = (b,h,lt), 256 thr, static LDS 40960B -> 4 blocks/CU
__global__ __launch_bounds__(256, 4) void qka_main_kernel(
    const float* __restrict__ qp_ws,          // [B,H,L,P] fp32
    const float* __restrict__ kp_ws,          // [B,H,S,P] fp32
    const unsigned short* __restrict__ vt_ws, // [B,H,D,S] bf16
    float* __restrict__ out_ctx,              // [B,L,H,D]
    float* __restrict__ out_attn)             // [B,H,L,S]
{
    __shared__ unsigned short kp[SS * PP];    // 8192 B, bf16 params
    __shared__ unsigned short Pm[TL * SS];    // 32768 B, normalized bf16 w (XOR-swizzled)

    const int t   = threadIdx.x;
    const int bid = blockIdx.x;
    const int lt  = bid & 63;
    const int h   = (bid >> 6) & 7;
    const int b   = bid >> 9;
    const int bh  = b * HH + h;

    // ---- stage kp as bf16 ----
    const float4* kps = reinterpret_cast<const float4*>(kp_ws + (size_t)bh * SS * PP);
    #pragma unroll
    for (int r = 0; r < 4; ++r) {
        int s = r * 256 + t;
        float4 kv = kps[s];
        uint2 pk;
        pk.x = cvt_pk_bf16(kv.x, kv.y);
        pk.y = cvt_pk_bf16(kv.z, kv.w);
        *reinterpret_cast<uint2*>(&kp[s * 4]) = pk;
    }
    __syncthreads();

    const int wv = t >> 6, lane = t & 63;
    const int r0 = wv * 4;                    // this wave owns rows r0..r0+3

    float4 q4[4];
    #pragma unroll
    for (int i = 0; i < 4; ++i)
        q4[i] = *reinterpret_cast<const float4*>(
            qp_ws + ((size_t)bh * LL + lt * TL + r0 + i) * PP);

    // ---- pass A: P = exp(score) kept in REGISTERS (packed bf16), Z in regs ----
    unsigned pk[4][8];
    float zacc[4] = {0.f, 0.f, 0.f, 0.f};
    #pragma unroll
    for (int c = 0; c < 8; ++c) {
        int s = c * 128 + lane * 2;
        uint4 kk = *reinterpret_cast<const uint4*>(&kp[s * 4]);  // params of s, s+1
        float ka0 = bf2f(kk.x & 0xffffu), ka1 = bf2f(kk.x >> 16);
        float ka2 = bf2f(kk.y & 0xffffu), ka3 = bf2f(kk.y >> 16);
        float kb0 = bf2f(kk.z & 0xffffu), kb1 = bf2f(kk.z >> 16);
        float kb2 = bf2f(kk.w & 0xffffu), kb3 = bf2f(kk.w >> 16);
        #pragma unroll
        for (int i = 0; i < 4; ++i) {
            float e0 = scoreP(q4[i], ka0, ka1, ka2, ka3);
            float e1 = scoreP(q4[i], kb0, kb1, kb2, kb3);
            zacc[i] += e0 + e1;
            pk[i][c] = cvt_pk_bf16(e0, e1);
        }
    }

    // ---- Z reduce (wave-private rows, no barrier) ----
    #pragma unroll
    for (int i = 0; i < 4; ++i) {
        float z = zacc[i];
        #pragma unroll
        for (int off = 1; off < 64; off <<= 1) z += __shfl_xor(z, off);
        zacc[i] = 1.0f / z;
    }

    // ---- store pass: normalize from regs, nt-store attn fp32, write bf16 w -> Pm ----
    #pragma unroll
    for (int i = 0; i < 4; ++i) {
        int row = r0 + i;
        float rz = zacc[i];
        unsigned sw = (row & 7) << 4;
        float* abase = out_attn + ((size_t)bh * LL + lt * TL + row) * SS + lane * 2;
        #pragma unroll
        for (int c = 0; c < 8; ++c) {
            unsigned p = pk[i][c];
            float w0 = bf2f(p & 0xffffu) * rz;
            float w1 = bf2f(p >> 16) * rz;
            floatx2 wv2 = {w0, w1};
            __builtin_nontemporal_store(wv2, reinterpret_cast<floatx2*>(abase + c * 128));
            unsigned byte = (unsigned)(row * 2048 + c * 256 + lane * 4) ^ sw;
            *reinterpret_cast<unsigned*>(reinterpret_cast<char*>(Pm) + byte) = cvt_pk_bf16(w0, w1);
        }
    }
    __syncthreads();   // all rows' w visible to all waves

    // ---- PV: ctx[16 l][64 d] via mfma 16x16x32 bf16; wave wv -> d0 = wv*16 ----
    const int d0 = wv * 16;
    const int fr = lane & 15;     // A row (l), B col (d)
    const int hi = lane >> 4;     // k-group
    floatx4 acc = {0.f, 0.f, 0.f, 0.f};
    const unsigned short* vtb = vt_ws + ((size_t)bh * DD + d0 + fr) * SS + hi * 8;
    const unsigned swf = (unsigned)((fr & 7) << 4);
    #pragma unroll 4
    for (int st = 0; st < 32; ++st) {
        unsigned abyte = (unsigned)(fr * 2048 + st * 64 + hi * 16) ^ swf;
        short8 afrag = *reinterpret_cast<const short8*>(
            reinterpret_cast<char*>(Pm) + abyte);
        short8 bfrag = *reinterpret_cast<const short8*>(vtb + st * 32);
        acc = __builtin_amdgcn_mfma_f32_16x16x32_bf16(afrag, bfrag, acc, 0, 0, 0);
    }
    // D: row m = hi*4 + r, col n = fr
    #pragma unroll
    for (int r = 0; r < 4; ++r) {
        int l = lt * TL + hi * 4 + r;
        __builtin_nontemporal_store(acc[r],
            out_ctx + (((size_t)b * LL + l) * HH + h) * DD + d0 + fr);
    }
}

extern "C" void kernel_launch(void* const* d_in, const int* in_sizes, int n_in,
                              void* d_out, int out_size, void* d_ws, size_t ws_size,
                              hipStream_t stream) {
    const float* Q  = (const float*)d_in[0];
    const float* K  = (const float*)d_in[1];
    const float* V  = (const float*)d_in[2];
    const float* Wq = (const float*)d_in[3];
    const float* bq = (const float*)d_in[4];
    const float* Wk = (const float*)d_in[5];
    const float* bk = (const float*)d_in[6];

    float* out_ctx  = (float*)d_out;                           // [B,L,H,D]
    float* out_attn = out_ctx + (size_t)BB * LL * HH * DD;     // [B,H,L,S]

    float* qp_ws = (float*)d_ws;                               // 256 KB
    float* kp_ws = qp_ws + (size_t)BB * HH * LL * PP;          // 256 KB
    unsigned short* vt_ws = (unsigned short*)(kp_ws + (size_t)BB * HH * SS * PP); // 2 MB bf16 V^T

    // K1: params (512 blocks) + V transpose (256 blocks)
    qka_prep_kernel<<<768, 256, 0, stream>>>(Q, K, V, Wq, bq, Wk, bk, qp_ws, kp_ws, vt_ws);

    // K2: fused scores/softmax/attn/PV
    qka_main_kernel<<<BB * HH * (LL / TL), 256, 0, stream>>>(
        qp_ws, kp_ws, vt_ws, out_ctx, out_attn);
}